// Round 1
// baseline (6588.869 us; speedup 1.0000x reference)
//
#include <hip/hip_runtime.h>

#define CC 64
#define SS 65536               // F*T
#define PLANE 4194304          // CC*SS floats per (b,part)
#define TEN_ELEMS 16777216     // 2*2*CC*SS floats per tensor

// ---------------- complex 1x1 conv + bias + BN-stats ----------------
__global__ __launch_bounds__(256) void cconv_kernel(
    const float* __restrict__ x, const float* __restrict__ W,
    const float* __restrict__ bias, float* __restrict__ y,
    float* __restrict__ stats)
{
  __shared__ float sW[8192];   // [(co*64+c)*2+p]
  __shared__ float sX[8192];   // [r*64+j], r = p*64+c
  const int tid = threadIdx.x;
  const int b = blockIdx.y;
  const int s0 = blockIdx.x << 6;

  for (int i = tid; i < 8192; i += 256) {
    int p = i >> 12, co = (i >> 6) & 63, c = i & 63;
    sW[(((co << 6) + c) << 1) + p] = W[i];
  }
  for (int i = tid; i < 8192; i += 256) {
    int r = i >> 6, j = i & 63;
    sX[i] = x[(size_t)((b << 7) + r) * SS + s0 + j];
  }
  __syncthreads();

  const int cg = tid & 31;       // column pair: cols 2cg, 2cg+1
  const int rg = tid >> 5;       // 0..7, rows rg*16..+15 (row = p*64+co)
  const int row0 = rg << 4;
  const int co0 = row0 & 63;
  const bool isyi = (row0 >= 64);

  float accA[16], accB[16];
  #pragma unroll
  for (int k = 0; k < 16; ++k) { accA[k] = 0.f; accB[k] = 0.f; }

  for (int c = 0; c < 64; ++c) {
    float2 xr = *(const float2*)&sX[(c << 6) + (cg << 1)];
    float2 xi = *(const float2*)&sX[((c + 64) << 6) + (cg << 1)];
    // yr = W0*xr - W1*xi ; yi = W0*xi + W1*xr
    float ux = isyi ? xi.x : xr.x;
    float uy = isyi ? xi.y : xr.y;
    float vx = isyi ? xr.x : -xi.x;
    float vy = isyi ? xr.y : -xi.y;
    #pragma unroll
    for (int k = 0; k < 16; ++k) {
      float2 w = *(const float2*)&sW[(((co0 + k) << 6) + c) << 1];
      accA[k] += w.x * ux + w.y * vx;
      accB[k] += w.x * uy + w.y * vy;
    }
  }

  #pragma unroll
  for (int k = 0; k < 16; ++k) {
    float bv = bias[row0 + k];          // bias laid (2,64) -> idx == row
    float a0 = accA[k] + bv;
    float a1 = accB[k] + bv;
    float sm = a0 + a1;
    float sq = a0 * a0 + a1 * a1;
    #pragma unroll
    for (int off = 1; off < 32; off <<= 1) {   // reduce over 32-lane half-wave
      sm += __shfl_xor(sm, off, 64);
      sq += __shfl_xor(sq, off, 64);
    }
    if (cg == 0) {
      atomicAdd(&stats[((row0 + k) << 1) + 0], sm);
      atomicAdd(&stats[((row0 + k) << 1) + 1], sq);
    }
    *(float2*)&y[(size_t)((b << 7) + row0 + k) * SS + s0 + (cg << 1)] =
        make_float2(a0, a1);
  }
}

// ---------------- BN finalize: scale/shift per (conv,part,channel) ----------
__global__ void bn_finalize(const float* __restrict__ stats,
                            const float* __restrict__ g,
                            const float* __restrict__ beta, int goff,
                            float* __restrict__ scale, float* __restrict__ shift)
{
  int i = blockIdx.x * 256 + threadIdx.x;     // 0..383 = [conv3][p][co]
  if (i >= 384) return;
  float sm = stats[i * 2], sq = stats[i * 2 + 1];
  const float inv = 1.f / 131072.f;           // B*F*T
  float mu = sm * inv;
  float var = sq * inv - mu * mu;
  float istd = rsqrtf(var + 1e-5f);
  int conv = i >> 7, pc = i & 127;
  float gg = g[goff + conv * 128 + pc];
  float bb = beta[goff + conv * 128 + pc];
  float sc = gg * istd;
  scale[i] = sc;
  shift[i] = bb - mu * sc;
}

// ---------------- BN apply + leaky relu (in place over 3 tensors) -----------
__global__ __launch_bounds__(256) void bn_apply(
    float* __restrict__ y, const float* __restrict__ scale,
    const float* __restrict__ shift)
{
  size_t i = (size_t)blockIdx.x * 256 + threadIdx.x;  // float4 index
  float4 v = ((float4*)y)[i];
  size_t fi = i << 2;
  int idx = (int)(fi >> 24) * 128 + (int)((fi >> 16) & 127);
  float sc = scale[idx], sh = shift[idx];
  float t;
  t = v.x * sc + sh; v.x = t > 0.f ? t : 0.01f * t;
  t = v.y * sc + sh; v.y = t > 0.f ? t : 0.01f * t;
  t = v.z * sc + sh; v.z = t > 0.f ? t : 0.01f * t;
  t = v.w * sc + sh; v.w = t > 0.f ? t : 0.01f * t;
  ((float4*)y)[i] = v;
}

// ---------------- complex scores: sr,si (split-K, atomic accumulate) --------
__global__ __launch_bounds__(256) void score_kernel(
    const float* __restrict__ q, const float* __restrict__ k,
    float* __restrict__ sr, float* __restrict__ si, int freq)
{
  __shared__ float sQ[2][16][68];
  __shared__ float sK[2][16][68];
  const int tid = threadIdx.x;
  const int tile = blockIdx.x;
  const int kc = blockIdx.y;
  const int b = blockIdx.z;
  const int n0 = (tile >> 2) << 6;
  const int m0 = (tile & 3) << 6;
  const int d0 = kc << 10;
  const float* qp = q + (size_t)b * 2 * PLANE;
  const float* kp = k + (size_t)b * 2 * PLANE;
  const int tn = tid & 15, tm = tid >> 4;

  float accr[16], acci[16];
  #pragma unroll
  for (int z = 0; z < 16; ++z) { accr[z] = 0.f; acci[z] = 0.f; }

  for (int dd = 0; dd < 1024; dd += 16) {
    for (int i = tid; i < 2048; i += 256) {
      int p = i >> 10;
      int dl, j;
      if (!freq) { j = i & 63; dl = (i >> 6) & 15; }
      else       { dl = i & 15; j = (i >> 4) & 63; }
      int dg = d0 + dd + dl;
      size_t addr = freq ? ((size_t)(dg >> 8) * 65536 + (dg & 255) + (size_t)(n0 + j) * 256)
                         : ((size_t)dg * 256 + n0 + j);
      sQ[p][dl][j] = qp[(size_t)p * PLANE + addr];
    }
    for (int i = tid; i < 2048; i += 256) {
      int p = i >> 10;
      int dl, j;
      if (!freq) { j = i & 63; dl = (i >> 6) & 15; }
      else       { dl = i & 15; j = (i >> 4) & 63; }
      int dg = d0 + dd + dl;
      size_t addr = freq ? ((size_t)(dg >> 8) * 65536 + (dg & 255) + (size_t)(m0 + j) * 256)
                         : ((size_t)dg * 256 + m0 + j);
      sK[p][dl][j] = kp[(size_t)p * PLANE + addr];
    }
    __syncthreads();
    for (int d = 0; d < 16; ++d) {
      float qr[4], qi[4], kr[4], ki[4];
      *(float4*)qr = *(const float4*)&sQ[0][d][tn << 2];
      *(float4*)qi = *(const float4*)&sQ[1][d][tn << 2];
      *(float4*)kr = *(const float4*)&sK[0][d][tm << 2];
      *(float4*)ki = *(const float4*)&sK[1][d][tm << 2];
      #pragma unroll
      for (int a2 = 0; a2 < 4; ++a2)
        #pragma unroll
        for (int c2 = 0; c2 < 4; ++c2) {
          accr[a2 * 4 + c2] += qr[a2] * kr[c2] + qi[a2] * ki[c2];
          acci[a2 * 4 + c2] += qi[a2] * kr[c2] - qr[a2] * ki[c2];
        }
    }
    __syncthreads();
  }
  #pragma unroll
  for (int a2 = 0; a2 < 4; ++a2)
    #pragma unroll
    for (int c2 = 0; c2 < 4; ++c2) {
      int n = n0 + (tn << 2) + a2;
      int m = m0 + (tm << 2) + c2;
      int oidx = (b << 16) + (n << 8) + m;
      atomicAdd(&sr[oidx], accr[a2 * 4 + c2]);
      atomicAdd(&si[oidx], acci[a2 * 4 + c2]);
    }
}

// ---------------- softmax over n (axis=1), per (b,m) column -----------------
__global__ __launch_bounds__(256) void softmax_kernel(
    const float* __restrict__ sr, const float* __restrict__ si,
    float* __restrict__ am)
{
  const int m = blockIdx.x & 255;
  const int b = blockIdx.x >> 8;
  const int n = threadIdx.x;
  const int idx = (b << 16) + (n << 8) + m;
  float vr = sr[idx], vi = si[idx];
  float mag = sqrtf(vr * vr + vi * vi);
  __shared__ float wmax[4];
  __shared__ float wsum[4];
  float mx = mag;
  #pragma unroll
  for (int off = 1; off < 64; off <<= 1)
    mx = fmaxf(mx, __shfl_xor(mx, off, 64));
  if ((threadIdx.x & 63) == 0) wmax[threadIdx.x >> 6] = mx;
  __syncthreads();
  mx = fmaxf(fmaxf(wmax[0], wmax[1]), fmaxf(wmax[2], wmax[3]));
  float e = expf(mag - mx);
  float sm = e;
  #pragma unroll
  for (int off = 1; off < 64; off <<= 1)
    sm += __shfl_xor(sm, off, 64);
  if ((threadIdx.x & 63) == 0) wsum[threadIdx.x >> 6] = sm;
  __syncthreads();
  float tot = wsum[0] + wsum[1] + wsum[2] + wsum[3];
  am[idx] = e / tot;
}

// ---------------- out[d,n] = sum_m a[n,m] * v[d,m] --------------------------
__global__ __launch_bounds__(256) void av_kernel(
    const float* __restrict__ am, const float* __restrict__ v,
    float* __restrict__ out, int freq, int accum)
{
  __shared__ float sV[32][68];   // [m][d]
  __shared__ float sA[32][68];   // [m][n]
  const int tid = threadIdx.x;
  const int d0 = blockIdx.x << 6;
  const int n0 = blockIdx.y << 6;
  const int bp = blockIdx.z;     // b*2+p
  const int b = bp >> 1;
  const float* vp = v + (size_t)bp * PLANE;
  float* op = out + (size_t)bp * PLANE;
  const int td = tid & 15, tn = tid >> 4;

  float acc[16];
  #pragma unroll
  for (int z = 0; z < 16; ++z) acc[z] = 0.f;

  for (int m0 = 0; m0 < 256; m0 += 32) {
    for (int i = tid; i < 2048; i += 256) {
      int dl, mj;
      size_t addr;
      if (!freq) { mj = i & 31; dl = i >> 5;
                   addr = (size_t)(d0 + dl) * 256 + m0 + mj; }
      else       { dl = i & 63; mj = i >> 6;
                   int dg = d0 + dl;
                   addr = (size_t)(dg >> 8) * 65536 + (dg & 255) + (size_t)(m0 + mj) * 256; }
      sV[mj][dl] = vp[addr];
    }
    for (int i = tid; i < 2048; i += 256) {
      int mj = i & 31, nl = i >> 5;
      sA[mj][nl] = am[(b << 16) + ((n0 + nl) << 8) + m0 + mj];
    }
    __syncthreads();
    for (int mm = 0; mm < 32; ++mm) {
      float vv[4], aa[4];
      *(float4*)vv = *(const float4*)&sV[mm][td << 2];
      *(float4*)aa = *(const float4*)&sA[mm][tn << 2];
      #pragma unroll
      for (int ni = 0; ni < 4; ++ni)
        #pragma unroll
        for (int di = 0; di < 4; ++di)
          acc[ni * 4 + di] += aa[ni] * vv[di];
    }
    __syncthreads();
  }

  if (!freq) {
    #pragma unroll
    for (int di = 0; di < 4; ++di) {
      float4 w = make_float4(acc[0 + di], acc[4 + di], acc[8 + di], acc[12 + di]);
      size_t addr = (size_t)(d0 + (td << 2) + di) * 256 + n0 + (tn << 2);
      if (accum) { float4 o = *(float4*)&op[addr];
                   w.x += o.x; w.y += o.y; w.z += o.z; w.w += o.w; }
      *(float4*)&op[addr] = w;
    }
  } else {
    int c = d0 >> 8;
    int t0 = (d0 & 255) + (td << 2);
    #pragma unroll
    for (int ni = 0; ni < 4; ++ni) {
      float4 w = make_float4(acc[ni * 4 + 0], acc[ni * 4 + 1],
                             acc[ni * 4 + 2], acc[ni * 4 + 3]);
      size_t addr = (size_t)c * 65536 + (size_t)(n0 + (tn << 2) + ni) * 256 + t0;
      if (accum) { float4 o = *(float4*)&op[addr];
                   w.x += o.x; w.y += o.y; w.z += o.z; w.w += o.w; }
      *(float4*)&op[addr] = w;
    }
  }
}

extern "C" void kernel_launch(void* const* d_in, const int* in_sizes, int n_in,
                              void* d_out, int out_size, void* d_ws, size_t ws_size,
                              hipStream_t stream) {
  const float* P    = (const float*)d_in[0];
  const float* Q    = (const float*)d_in[1];
  const float* W    = (const float*)d_in[2];
  const float* bias = (const float*)d_in[3];
  const float* g    = (const float*)d_in[4];
  const float* beta = (const float*)d_in[5];
  float* out = (float*)d_out;
  float* ws  = (float*)d_ws;

  // workspace layout (~203 MB)
  float* Y0    = ws;                      // qt
  float* Y1    = Y0 + TEN_ELEMS;          // kt
  float* Y2    = Y1 + TEN_ELEMS;          // vt
  float* SR    = Y2 + TEN_ELEMS;          // 131072
  float* SI    = SR + 131072;
  float* AM    = SI + 131072;
  float* STATS = AM + 131072;             // 768
  float* SCALE = STATS + 768;             // 384
  float* SHIFT = SCALE + 384;             // 384

  for (int phase = 0; phase < 2; ++phase) {
    int j0 = phase * 3;
    int freq = phase;
    hipMemsetAsync(STATS, 0, 768 * sizeof(float), stream);
    cconv_kernel<<<dim3(1024, 2), 256, 0, stream>>>(
        Q, W + (size_t)j0 * 8192, bias + j0 * 128, Y0, STATS);
    cconv_kernel<<<dim3(1024, 2), 256, 0, stream>>>(
        P, W + (size_t)(j0 + 1) * 8192, bias + (j0 + 1) * 128, Y1, STATS + 256);
    cconv_kernel<<<dim3(1024, 2), 256, 0, stream>>>(
        P, W + (size_t)(j0 + 2) * 8192, bias + (j0 + 2) * 128, Y2, STATS + 512);
    bn_finalize<<<2, 256, 0, stream>>>(STATS, g, beta, j0 * 128, SCALE, SHIFT);
    bn_apply<<<49152, 256, 0, stream>>>(Y0, SCALE, SHIFT);   // covers Y0..Y2
    hipMemsetAsync(SR, 0, 2 * 131072 * sizeof(float), stream);
    score_kernel<<<dim3(16, 16, 2), 256, 0, stream>>>(Y0, Y1, SR, SI, freq);
    softmax_kernel<<<512, 256, 0, stream>>>(SR, SI, AM);
    av_kernel<<<dim3(256, 4, 4), 256, 0, stream>>>(AM, Y2, out, freq, phase);
  }
}

// Round 3
// 4142.154 us; speedup vs baseline: 1.5907x; 1.5907x over previous
//
#include <hip/hip_runtime.h>
#include <math.h>

#define SS 65536               // F*T
#define PLANE 4194304          // CC*SS floats per (b,part)
#define TEN_ELEMS 16777216     // 2*2*CC*SS floats per tensor

typedef __bf16 bf16x8 __attribute__((ext_vector_type(8)));
typedef float  f32x4  __attribute__((ext_vector_type(4)));

__device__ inline f32x4 mfma16(bf16x8 a, bf16x8 b, f32x4 c) {
  return __builtin_amdgcn_mfma_f32_16x16x32_bf16(a, b, c, 0, 0, 0);
}

// ============ complex 1x1 conv (split-bf16 MFMA) + bias + BN stats ==========
// x: [b][p][c][65536] fp32.  Wj: [2][64][64] fp32.  y: [b][p][co][65536] fp32.
// Output tile: 128 rows (p*64+co) x 64 spatial, K = 128 (pi*64+c).
__global__ __launch_bounds__(256) void cconv_mfma(
    const float* __restrict__ x, const float* __restrict__ Wj,
    const float* __restrict__ bias, float* __restrict__ y,
    float* __restrict__ stats)
{
  __shared__ __align__(16) __bf16 sBh[64 * 136];   // [s][pc] hi
  __shared__ __align__(16) __bf16 sBl[64 * 136];   // [s][pc] lo
  const int tid = threadIdx.x;
  const int b = blockIdx.y;
  const int s0 = blockIdx.x << 6;
  const int w = tid >> 6, q = (tid >> 4) & 3, ln = tid & 15;

  // A fragments: block-complex W matrix [[Wr,-Wi],[Wi,Wr]], split hi/lo.
  // A[m = lane&15][k = quad*8+j]; rows handled: w*32 + mt*16 + ln.
  bf16x8 ah[2][4], al[2][4];
#pragma unroll
  for (int mt = 0; mt < 2; ++mt) {
    int row = w * 32 + mt * 16 + ln;
    int po = row >> 6, co = row & 63;
#pragma unroll
    for (int ks = 0; ks < 4; ++ks) {
      bf16x8 vh, vl;
#pragma unroll
      for (int j = 0; j < 8; ++j) {
        int k = ks * 32 + q * 8 + j;
        int pi = k >> 6, c = k & 63;
        float v = Wj[((po ^ pi) << 12) + co * 64 + c];
        if (po == 0 && pi == 1) v = -v;
        __bf16 h = (__bf16)v;
        vh[j] = h;
        vl[j] = (__bf16)(v - (float)h);
      }
      ah[mt][ks] = vh; al[mt][ks] = vl;
    }
  }

  // Stage x tile (128 pc x 64 s) into LDS transposed [s][pc], split hi/lo.
#pragma unroll
  for (int ph = 0; ph < 2; ++ph) {
    int pc = ph * 64 + (tid & 63);
    const float* rowp = x + (size_t)(b * 128 + pc) * SS + s0;
#pragma unroll
    for (int sh2 = 0; sh2 < 2; ++sh2)
#pragma unroll
      for (int sc2 = 0; sc2 < 2; ++sc2) {
        int sl = ((tid >> 6) << 3) + sh2 * 32 + sc2 * 4;
        float4 rd = *(const float4*)&rowp[sl];
        float vv[4] = {rd.x, rd.y, rd.z, rd.w};
#pragma unroll
        for (int e = 0; e < 4; ++e) {
          __bf16 h = (__bf16)vv[e];
          sBh[(sl + e) * 136 + pc] = h;
          sBl[(sl + e) * 136 + pc] = (__bf16)(vv[e] - (float)h);
        }
      }
  }
  __syncthreads();

  f32x4 zero = {0.f, 0.f, 0.f, 0.f};
  f32x4 acc[2][4];
#pragma unroll
  for (int mt = 0; mt < 2; ++mt)
#pragma unroll
    for (int nt = 0; nt < 4; ++nt) acc[mt][nt] = zero;

#pragma unroll
  for (int ks = 0; ks < 4; ++ks) {
    bf16x8 bh[4], bl[4];
#pragma unroll
    for (int nt = 0; nt < 4; ++nt) {
      int off = (nt * 16 + ln) * 136 + ks * 32 + q * 8;
      bh[nt] = *(const bf16x8*)&sBh[off];
      bl[nt] = *(const bf16x8*)&sBl[off];
    }
#pragma unroll
    for (int mt = 0; mt < 2; ++mt)
#pragma unroll
      for (int nt = 0; nt < 4; ++nt) {
        acc[mt][nt] = mfma16(ah[mt][ks], bh[nt], acc[mt][nt]);   // hi*hi
        acc[mt][nt] = mfma16(ah[mt][ks], bl[nt], acc[mt][nt]);   // hi*lo
        acc[mt][nt] = mfma16(al[mt][ks], bh[nt], acc[mt][nt]);   // lo*hi
      }
  }

  // Epilogue: bias, BN stats (sum/sumsq per row over 64 cols), store fp32.
  // D layout: row = q*4 + r, col = lane&15 (m89-verified).
#pragma unroll
  for (int mt = 0; mt < 2; ++mt) {
    int rowb = w * 32 + mt * 16 + q * 4;
#pragma unroll
    for (int r = 0; r < 4; ++r) {
      float bv = bias[rowb + r];
      float vs[4];
      float sm = 0.f, sq = 0.f;
#pragma unroll
      for (int nt = 0; nt < 4; ++nt) {
        float v = acc[mt][nt][r] + bv;
        vs[nt] = v; sm += v; sq += v * v;
      }
#pragma unroll
      for (int off = 1; off < 16; off <<= 1) {   // reduce over the 16 lanes ln
        sm += __shfl_xor(sm, off, 64);
        sq += __shfl_xor(sq, off, 64);
      }
      if (ln == 0) {
        atomicAdd(&stats[(rowb + r) * 2 + 0], sm);
        atomicAdd(&stats[(rowb + r) * 2 + 1], sq);
      }
#pragma unroll
      for (int nt = 0; nt < 4; ++nt)
        y[(size_t)((b << 7) + rowb + r) * SS + s0 + nt * 16 + ln] = vs[nt];
    }
  }
}

// ---------------- BN finalize: scale/shift per (conv,part,channel) ----------
__global__ void bn_finalize(const float* __restrict__ stats,
                            const float* __restrict__ g,
                            const float* __restrict__ beta, int goff,
                            float* __restrict__ scale, float* __restrict__ shift)
{
  int i = blockIdx.x * 256 + threadIdx.x;     // 0..383 = [conv3][p][co]
  if (i >= 384) return;
  float sm = stats[i * 2], sq = stats[i * 2 + 1];
  const float inv = 1.f / 131072.f;           // B*F*T
  float mu = sm * inv;
  float var = sq * inv - mu * mu;
  float istd = rsqrtf(var + 1e-5f);
  int conv = i >> 7, pc = i & 127;
  float gg = g[goff + conv * 128 + pc];
  float bb = beta[goff + conv * 128 + pc];
  float sc = gg * istd;
  scale[i] = sc;
  shift[i] = bb - mu * sc;
}

// ---------------- BN apply + leaky relu (in place over 3 tensors) -----------
__global__ __launch_bounds__(256) void bn_apply(
    float* __restrict__ y, const float* __restrict__ scale,
    const float* __restrict__ shift)
{
  size_t i = (size_t)blockIdx.x * 256 + threadIdx.x;  // float4 index
  float4 v = ((float4*)y)[i];
  size_t fi = i << 2;
  int idx = (int)(fi >> 24) * 128 + (int)((fi >> 16) & 127);
  float sc = scale[idx], sh = shift[idx];
  float t;
  t = v.x * sc + sh; v.x = t > 0.f ? t : 0.01f * t;
  t = v.y * sc + sh; v.y = t > 0.f ? t : 0.01f * t;
  t = v.z * sc + sh; v.z = t > 0.f ? t : 0.01f * t;
  t = v.w * sc + sh; v.w = t > 0.f ? t : 0.01f * t;
  ((float4*)y)[i] = v;
}

// ---------------- complex scores: sr,si (split-K, atomic accumulate) --------
__global__ __launch_bounds__(256) void score_kernel(
    const float* __restrict__ q, const float* __restrict__ k,
    float* __restrict__ sr, float* __restrict__ si, int freq)
{
  __shared__ float sQ[2][16][68];
  __shared__ float sK[2][16][68];
  const int tid = threadIdx.x;
  const int tile = blockIdx.x;
  const int kc = blockIdx.y;
  const int b = blockIdx.z;
  const int n0 = (tile >> 2) << 6;
  const int m0 = (tile & 3) << 6;
  const int d0 = kc << 10;
  const float* qp = q + (size_t)b * 2 * PLANE;
  const float* kp = k + (size_t)b * 2 * PLANE;
  const int tn = tid & 15, tm = tid >> 4;

  float accr[16], acci[16];
  #pragma unroll
  for (int z = 0; z < 16; ++z) { accr[z] = 0.f; acci[z] = 0.f; }

  for (int dd = 0; dd < 1024; dd += 16) {
    for (int i = tid; i < 2048; i += 256) {
      int p = i >> 10;
      int dl, j;
      if (!freq) { j = i & 63; dl = (i >> 6) & 15; }
      else       { dl = i & 15; j = (i >> 4) & 63; }
      int dg = d0 + dd + dl;
      size_t addr = freq ? ((size_t)(dg >> 8) * 65536 + (dg & 255) + (size_t)(n0 + j) * 256)
                         : ((size_t)dg * 256 + n0 + j);
      sQ[p][dl][j] = qp[(size_t)p * PLANE + addr];
    }
    for (int i = tid; i < 2048; i += 256) {
      int p = i >> 10;
      int dl, j;
      if (!freq) { j = i & 63; dl = (i >> 6) & 15; }
      else       { dl = i & 15; j = (i >> 4) & 63; }
      int dg = d0 + dd + dl;
      size_t addr = freq ? ((size_t)(dg >> 8) * 65536 + (dg & 255) + (size_t)(m0 + j) * 256)
                         : ((size_t)dg * 256 + m0 + j);
      sK[p][dl][j] = kp[(size_t)p * PLANE + addr];
    }
    __syncthreads();
    for (int d = 0; d < 16; ++d) {
      float qr[4], qi[4], kr[4], ki[4];
      *(float4*)qr = *(const float4*)&sQ[0][d][tn << 2];
      *(float4*)qi = *(const float4*)&sQ[1][d][tn << 2];
      *(float4*)kr = *(const float4*)&sK[0][d][tm << 2];
      *(float4*)ki = *(const float4*)&sK[1][d][tm << 2];
      #pragma unroll
      for (int a2 = 0; a2 < 4; ++a2)
        #pragma unroll
        for (int c2 = 0; c2 < 4; ++c2) {
          accr[a2 * 4 + c2] += qr[a2] * kr[c2] + qi[a2] * ki[c2];
          acci[a2 * 4 + c2] += qi[a2] * kr[c2] - qr[a2] * ki[c2];
        }
    }
    __syncthreads();
  }
  #pragma unroll
  for (int a2 = 0; a2 < 4; ++a2)
    #pragma unroll
    for (int c2 = 0; c2 < 4; ++c2) {
      int n = n0 + (tn << 2) + a2;
      int m = m0 + (tm << 2) + c2;
      int oidx = (b << 16) + (n << 8) + m;
      atomicAdd(&sr[oidx], accr[a2 * 4 + c2]);
      atomicAdd(&si[oidx], acci[a2 * 4 + c2]);
    }
}

// ---------------- softmax over n (axis=1), per (b,m) column -----------------
__global__ __launch_bounds__(256) void softmax_kernel(
    const float* __restrict__ sr, const float* __restrict__ si,
    float* __restrict__ am)
{
  const int m = blockIdx.x & 255;
  const int b = blockIdx.x >> 8;
  const int n = threadIdx.x;
  const int idx = (b << 16) + (n << 8) + m;
  float vr = sr[idx], vi = si[idx];
  float mag = sqrtf(vr * vr + vi * vi);
  __shared__ float wmax[4];
  __shared__ float wsum[4];
  float mx = mag;
  #pragma unroll
  for (int off = 1; off < 64; off <<= 1)
    mx = fmaxf(mx, __shfl_xor(mx, off, 64));
  if ((threadIdx.x & 63) == 0) wmax[threadIdx.x >> 6] = mx;
  __syncthreads();
  mx = fmaxf(fmaxf(wmax[0], wmax[1]), fmaxf(wmax[2], wmax[3]));
  float e = expf(mag - mx);
  float sm = e;
  #pragma unroll
  for (int off = 1; off < 64; off <<= 1)
    sm += __shfl_xor(sm, off, 64);
  if ((threadIdx.x & 63) == 0) wsum[threadIdx.x >> 6] = sm;
  __syncthreads();
  float tot = wsum[0] + wsum[1] + wsum[2] + wsum[3];
  am[idx] = e / tot;
}

// ---------------- out[d,n] = sum_m a[n,m] * v[d,m] --------------------------
__global__ __launch_bounds__(256) void av_kernel(
    const float* __restrict__ am, const float* __restrict__ v,
    float* __restrict__ out, int freq, int accum)
{
  __shared__ float sV[32][68];   // [m][d]
  __shared__ float sA[32][68];   // [m][n]
  const int tid = threadIdx.x;
  const int d0 = blockIdx.x << 6;
  const int n0 = blockIdx.y << 6;
  const int bp = blockIdx.z;     // b*2+p
  const int b = bp >> 1;
  const float* vp = v + (size_t)bp * PLANE;
  float* op = out + (size_t)bp * PLANE;
  const int td = tid & 15, tn = tid >> 4;

  float acc[16];
  #pragma unroll
  for (int z = 0; z < 16; ++z) acc[z] = 0.f;

  for (int m0 = 0; m0 < 256; m0 += 32) {
    for (int i = tid; i < 2048; i += 256) {
      int dl, mj;
      size_t addr;
      if (!freq) { mj = i & 31; dl = i >> 5;
                   addr = (size_t)(d0 + dl) * 256 + m0 + mj; }
      else       { dl = i & 63; mj = i >> 6;
                   int dg = d0 + dl;
                   addr = (size_t)(dg >> 8) * 65536 + (dg & 255) + (size_t)(m0 + mj) * 256; }
      sV[mj][dl] = vp[addr];
    }
    for (int i = tid; i < 2048; i += 256) {
      int mj = i & 31, nl = i >> 5;
      sA[mj][nl] = am[(b << 16) + ((n0 + nl) << 8) + m0 + mj];
    }
    __syncthreads();
    for (int mm = 0; mm < 32; ++mm) {
      float vv[4], aa[4];
      *(float4*)vv = *(const float4*)&sV[mm][td << 2];
      *(float4*)aa = *(const float4*)&sA[mm][tn << 2];
      #pragma unroll
      for (int ni = 0; ni < 4; ++ni)
        #pragma unroll
        for (int di = 0; di < 4; ++di)
          acc[ni * 4 + di] += aa[ni] * vv[di];
    }
    __syncthreads();
  }

  if (!freq) {
    #pragma unroll
    for (int di = 0; di < 4; ++di) {
      float4 w = make_float4(acc[0 + di], acc[4 + di], acc[8 + di], acc[12 + di]);
      size_t addr = (size_t)(d0 + (td << 2) + di) * 256 + n0 + (tn << 2);
      if (accum) { float4 o = *(float4*)&op[addr];
                   w.x += o.x; w.y += o.y; w.z += o.z; w.w += o.w; }
      *(float4*)&op[addr] = w;
    }
  } else {
    int c = d0 >> 8;
    int t0 = (d0 & 255) + (td << 2);
    #pragma unroll
    for (int ni = 0; ni < 4; ++ni) {
      float4 w = make_float4(acc[ni * 4 + 0], acc[ni * 4 + 1],
                             acc[ni * 4 + 2], acc[ni * 4 + 3]);
      size_t addr = (size_t)c * 65536 + (size_t)(n0 + (tn << 2) + ni) * 256 + t0;
      if (accum) { float4 o = *(float4*)&op[addr];
                   w.x += o.x; w.y += o.y; w.z += o.z; w.w += o.w; }
      *(float4*)&op[addr] = w;
    }
  }
}

extern "C" void kernel_launch(void* const* d_in, const int* in_sizes, int n_in,
                              void* d_out, int out_size, void* d_ws, size_t ws_size,
                              hipStream_t stream) {
  const float* P    = (const float*)d_in[0];
  const float* Q    = (const float*)d_in[1];
  const float* W    = (const float*)d_in[2];
  const float* bias = (const float*)d_in[3];
  const float* g    = (const float*)d_in[4];
  const float* beta = (const float*)d_in[5];
  float* out = (float*)d_out;
  float* ws  = (float*)d_ws;

  // workspace layout (~203 MB)
  float* Y0    = ws;                      // qt
  float* Y1    = Y0 + TEN_ELEMS;          // kt
  float* Y2    = Y1 + TEN_ELEMS;          // vt
  float* SR    = Y2 + TEN_ELEMS;          // 131072
  float* SI    = SR + 131072;
  float* AM    = SI + 131072;
  float* STATS = AM + 131072;             // 768
  float* SCALE = STATS + 768;             // 384
  float* SHIFT = SCALE + 384;             // 384

  for (int phase = 0; phase < 2; ++phase) {
    int j0 = phase * 3;
    int freq = phase;
    hipMemsetAsync(STATS, 0, 768 * sizeof(float), stream);
    cconv_mfma<<<dim3(1024, 2), 256, 0, stream>>>(
        Q, W + (size_t)j0 * 8192, bias + j0 * 128, Y0, STATS);
    cconv_mfma<<<dim3(1024, 2), 256, 0, stream>>>(
        P, W + (size_t)(j0 + 1) * 8192, bias + (j0 + 1) * 128, Y1, STATS + 256);
    cconv_mfma<<<dim3(1024, 2), 256, 0, stream>>>(
        P, W + (size_t)(j0 + 2) * 8192, bias + (j0 + 2) * 128, Y2, STATS + 512);
    bn_finalize<<<2, 256, 0, stream>>>(STATS, g, beta, j0 * 128, SCALE, SHIFT);
    bn_apply<<<49152, 256, 0, stream>>>(Y0, SCALE, SHIFT);   // covers Y0..Y2
    hipMemsetAsync(SR, 0, 2 * 131072 * sizeof(float), stream);
    score_kernel<<<dim3(16, 16, 2), 256, 0, stream>>>(Y0, Y1, SR, SI, freq);
    softmax_kernel<<<512, 256, 0, stream>>>(SR, SI, AM);
    av_kernel<<<dim3(256, 4, 4), 256, 0, stream>>>(AM, Y2, out, freq, phase);
  }
}

// Round 4
// 3276.647 us; speedup vs baseline: 2.0109x; 1.2641x over previous
//
#include <hip/hip_runtime.h>
#include <math.h>

#define SS 65536               // F*T
#define PLANE 4194304          // CC*SS floats per (b,part)
#define TEN_ELEMS 16777216     // 2*2*CC*SS floats per tensor

typedef __bf16 bf16x8 __attribute__((ext_vector_type(8)));
typedef __bf16 bf16x4v __attribute__((ext_vector_type(4)));
typedef float  f32x4  __attribute__((ext_vector_type(4)));

__device__ inline f32x4 mfma16(bf16x8 a, bf16x8 b, f32x4 c) {
  return __builtin_amdgcn_mfma_f32_16x16x32_bf16(a, b, c, 0, 0, 0);
}
__device__ inline bf16x8 neg8(bf16x8 v) {
  union { bf16x8 b; unsigned u[4]; } t; t.b = v;
#pragma unroll
  for (int i = 0; i < 4; ++i) t.u[i] ^= 0x80008000u;
  return t.b;
}

// ============ complex 1x1 conv (split-bf16 MFMA) + bias + BN stats ==========
__global__ __launch_bounds__(256) void cconv_mfma(
    const float* __restrict__ x, const float* __restrict__ Wj,
    const float* __restrict__ bias, float* __restrict__ y,
    float* __restrict__ stats)
{
  __shared__ __align__(16) __bf16 sBh[64 * 136];   // [s][pc] hi
  __shared__ __align__(16) __bf16 sBl[64 * 136];   // [s][pc] lo
  const int tid = threadIdx.x;
  const int b = blockIdx.y;
  const int s0 = blockIdx.x << 6;
  const int w = tid >> 6, q = (tid >> 4) & 3, ln = tid & 15;

  bf16x8 ah[2][4], al[2][4];
#pragma unroll
  for (int mt = 0; mt < 2; ++mt) {
    int row = w * 32 + mt * 16 + ln;
    int po = row >> 6, co = row & 63;
#pragma unroll
    for (int ks = 0; ks < 4; ++ks) {
      bf16x8 vh, vl;
#pragma unroll
      for (int j = 0; j < 8; ++j) {
        int k = ks * 32 + q * 8 + j;
        int pi = k >> 6, c = k & 63;
        float v = Wj[((po ^ pi) << 12) + co * 64 + c];
        if (po == 0 && pi == 1) v = -v;
        __bf16 h = (__bf16)v;
        vh[j] = h;
        vl[j] = (__bf16)(v - (float)h);
      }
      ah[mt][ks] = vh; al[mt][ks] = vl;
    }
  }

#pragma unroll
  for (int ph = 0; ph < 2; ++ph) {
    int pc = ph * 64 + (tid & 63);
    const float* rowp = x + (size_t)(b * 128 + pc) * SS + s0;
#pragma unroll
    for (int sh2 = 0; sh2 < 2; ++sh2)
#pragma unroll
      for (int sc2 = 0; sc2 < 2; ++sc2) {
        int sl = ((tid >> 6) << 3) + sh2 * 32 + sc2 * 4;
        float4 rd = *(const float4*)&rowp[sl];
        float vv[4] = {rd.x, rd.y, rd.z, rd.w};
#pragma unroll
        for (int e = 0; e < 4; ++e) {
          __bf16 h = (__bf16)vv[e];
          sBh[(sl + e) * 136 + pc] = h;
          sBl[(sl + e) * 136 + pc] = (__bf16)(vv[e] - (float)h);
        }
      }
  }
  __syncthreads();

  f32x4 zero = {0.f, 0.f, 0.f, 0.f};
  f32x4 acc[2][4];
#pragma unroll
  for (int mt = 0; mt < 2; ++mt)
#pragma unroll
    for (int nt = 0; nt < 4; ++nt) acc[mt][nt] = zero;

#pragma unroll
  for (int ks = 0; ks < 4; ++ks) {
    bf16x8 bh[4], bl[4];
#pragma unroll
    for (int nt = 0; nt < 4; ++nt) {
      int off = (nt * 16 + ln) * 136 + ks * 32 + q * 8;
      bh[nt] = *(const bf16x8*)&sBh[off];
      bl[nt] = *(const bf16x8*)&sBl[off];
    }
#pragma unroll
    for (int mt = 0; mt < 2; ++mt)
#pragma unroll
      for (int nt = 0; nt < 4; ++nt) {
        acc[mt][nt] = mfma16(ah[mt][ks], bh[nt], acc[mt][nt]);
        acc[mt][nt] = mfma16(ah[mt][ks], bl[nt], acc[mt][nt]);
        acc[mt][nt] = mfma16(al[mt][ks], bh[nt], acc[mt][nt]);
      }
  }

#pragma unroll
  for (int mt = 0; mt < 2; ++mt) {
    int rowb = w * 32 + mt * 16 + q * 4;
#pragma unroll
    for (int r = 0; r < 4; ++r) {
      float bv = bias[rowb + r];
      float vs[4];
      float sm = 0.f, sq = 0.f;
#pragma unroll
      for (int nt = 0; nt < 4; ++nt) {
        float v = acc[mt][nt][r] + bv;
        vs[nt] = v; sm += v; sq += v * v;
      }
#pragma unroll
      for (int off = 1; off < 16; off <<= 1) {
        sm += __shfl_xor(sm, off, 64);
        sq += __shfl_xor(sq, off, 64);
      }
      if (ln == 0) {
        atomicAdd(&stats[(rowb + r) * 2 + 0], sm);
        atomicAdd(&stats[(rowb + r) * 2 + 1], sq);
      }
#pragma unroll
      for (int nt = 0; nt < 4; ++nt)
        y[(size_t)((b << 7) + rowb + r) * SS + s0 + nt * 16 + ln] = vs[nt];
    }
  }
}

// ---------------- BN finalize ----------------------------------------------
__global__ void bn_finalize(const float* __restrict__ stats,
                            const float* __restrict__ g,
                            const float* __restrict__ beta, int goff,
                            float* __restrict__ scale, float* __restrict__ shift)
{
  int i = blockIdx.x * 256 + threadIdx.x;
  if (i >= 384) return;
  float sm = stats[i * 2], sq = stats[i * 2 + 1];
  const float inv = 1.f / 131072.f;
  float mu = sm * inv;
  float var = sq * inv - mu * mu;
  float istd = rsqrtf(var + 1e-5f);
  int conv = i >> 7, pc = i & 127;
  float gg = g[goff + conv * 128 + pc];
  float bb = beta[goff + conv * 128 + pc];
  float sc = gg * istd;
  scale[i] = sc;
  shift[i] = bb - mu * sc;
}

// ---------------- BN apply + leaky relu ------------------------------------
__global__ __launch_bounds__(256) void bn_apply(
    float* __restrict__ y, const float* __restrict__ scale,
    const float* __restrict__ shift)
{
  size_t i = (size_t)blockIdx.x * 256 + threadIdx.x;
  float4 v = ((float4*)y)[i];
  size_t fi = i << 2;
  int idx = (int)(fi >> 24) * 128 + (int)((fi >> 16) & 127);
  float sc = scale[idx], sh = shift[idx];
  float t;
  t = v.x * sc + sh; v.x = t > 0.f ? t : 0.01f * t;
  t = v.y * sc + sh; v.y = t > 0.f ? t : 0.01f * t;
  t = v.z * sc + sh; v.z = t > 0.f ? t : 0.01f * t;
  t = v.w * sc + sh; v.w = t > 0.f ? t : 0.01f * t;
  ((float4*)y)[i] = v;
}

// ============ complex scores (split-bf16 MFMA, split-K, atomics) ============
// q,k: [b][p][c][65536] fp32 post-BN. time d=(c*256+f? no: d*256+tok);
//   time:  element [p][d][tok]   -> qp[p*PLANE + d*256 + tok]
//   freq:  element [p][d][tok]   -> qp[p*PLANE + (d>>8)*65536 + (d&255) + tok*256]
__global__ __launch_bounds__(256) void score_mfma(
    const float* __restrict__ qg, const float* __restrict__ kg,
    float* __restrict__ SR, float* __restrict__ SI, int freq)
{
  __shared__ __align__(16) __bf16 sQh[2 * 128 * 40], sQl[2 * 128 * 40];
  __shared__ __align__(16) __bf16 sKh[2 * 64 * 40],  sKl[2 * 64 * 40];
  const int tid = threadIdx.x;
  const int n0 = (blockIdx.x >> 2) * 128, m0 = (blockIdx.x & 3) * 64;
  const int d0 = blockIdx.y * 1024;
  const int b = blockIdx.z;
  const int w = tid >> 6, q4 = (tid >> 4) & 3, ln = tid & 15;
  const float* qp = qg + (size_t)b * 2 * PLANE;
  const float* kp = kg + (size_t)b * 2 * PLANE;

  f32x4 zero = {0.f, 0.f, 0.f, 0.f};
  f32x4 accr[2][4], acci[2][4];
#pragma unroll
  for (int st = 0; st < 2; ++st)
#pragma unroll
    for (int mt = 0; mt < 4; ++mt) { accr[st][mt] = zero; acci[st][mt] = zero; }

  for (int ch = 0; ch < 32; ++ch) {
    const int dd = d0 + ch * 32;
    if (!freq) {
      // load float4 along tokens, transpose-scatter into LDS [tok][d]
#pragma unroll
      for (int r = 0; r < 8; ++r) {
        int u = tid + 256 * r;
        int tok4 = u & 31, dl = (u >> 5) & 31, p = u >> 10;
        float4 v4 = *(const float4*)&qp[(size_t)p * PLANE +
                                        (size_t)(dd + dl) * 256 + n0 + tok4 * 4];
        float vv[4] = {v4.x, v4.y, v4.z, v4.w};
#pragma unroll
        for (int e = 0; e < 4; ++e) {
          __bf16 h = (__bf16)vv[e];
          sQh[(p * 128 + tok4 * 4 + e) * 40 + dl] = h;
          sQl[(p * 128 + tok4 * 4 + e) * 40 + dl] = (__bf16)(vv[e] - (float)h);
        }
      }
#pragma unroll
      for (int r = 0; r < 4; ++r) {
        int u = tid + 256 * r;
        int tok4 = u & 15, dl = (u >> 4) & 31, p = u >> 9;
        float4 v4 = *(const float4*)&kp[(size_t)p * PLANE +
                                        (size_t)(dd + dl) * 256 + m0 + tok4 * 4];
        float vv[4] = {v4.x, v4.y, v4.z, v4.w};
#pragma unroll
        for (int e = 0; e < 4; ++e) {
          __bf16 h = (__bf16)vv[e];
          sKh[(p * 64 + tok4 * 4 + e) * 40 + dl] = h;
          sKl[(p * 64 + tok4 * 4 + e) * 40 + dl] = (__bf16)(vv[e] - (float)h);
        }
      }
    } else {
      // d contiguous in memory (t direction) -> float4 along d
      const int c = dd >> 8, t0c = dd & 255;
#pragma unroll
      for (int r = 0; r < 8; ++r) {
        int u = tid + 256 * r;
        int dc = u & 7, tok = (u >> 3) & 127, p = u >> 10;
        float4 v4 = *(const float4*)&qp[(size_t)p * PLANE + (size_t)c * 65536 +
                                        t0c + dc * 4 + (size_t)(n0 + tok) * 256];
        float vv[4] = {v4.x, v4.y, v4.z, v4.w};
        bf16x4v hv, lv;
#pragma unroll
        for (int e = 0; e < 4; ++e) {
          __bf16 h = (__bf16)vv[e];
          hv[e] = h; lv[e] = (__bf16)(vv[e] - (float)h);
        }
        *(bf16x4v*)&sQh[(p * 128 + tok) * 40 + dc * 4] = hv;
        *(bf16x4v*)&sQl[(p * 128 + tok) * 40 + dc * 4] = lv;
      }
#pragma unroll
      for (int r = 0; r < 4; ++r) {
        int u = tid + 256 * r;
        int dc = u & 7, tok = (u >> 3) & 63, p = u >> 9;
        float4 v4 = *(const float4*)&kp[(size_t)p * PLANE + (size_t)c * 65536 +
                                        t0c + dc * 4 + (size_t)(m0 + tok) * 256];
        float vv[4] = {v4.x, v4.y, v4.z, v4.w};
        bf16x4v hv, lv;
#pragma unroll
        for (int e = 0; e < 4; ++e) {
          __bf16 h = (__bf16)vv[e];
          hv[e] = h; lv[e] = (__bf16)(vv[e] - (float)h);
        }
        *(bf16x4v*)&sKh[(p * 64 + tok) * 40 + dc * 4] = hv;
        *(bf16x4v*)&sKl[(p * 64 + tok) * 40 + dc * 4] = lv;
      }
    }
    __syncthreads();

    bf16x8 qh[2][2], ql2[2][2], nqh[2], nql[2];
#pragma unroll
    for (int st = 0; st < 2; ++st) {
      int tokn = w * 32 + st * 16 + ln;
#pragma unroll
      for (int p = 0; p < 2; ++p) {
        qh[st][p]  = *(const bf16x8*)&sQh[(p * 128 + tokn) * 40 + q4 * 8];
        ql2[st][p] = *(const bf16x8*)&sQl[(p * 128 + tokn) * 40 + q4 * 8];
      }
      nqh[st] = neg8(qh[st][0]);
      nql[st] = neg8(ql2[st][0]);
    }
#pragma unroll
    for (int mt = 0; mt < 4; ++mt) {
      int tk = mt * 16 + ln;
      bf16x8 krh = *(const bf16x8*)&sKh[tk * 40 + q4 * 8];
      bf16x8 krl = *(const bf16x8*)&sKl[tk * 40 + q4 * 8];
      bf16x8 kih = *(const bf16x8*)&sKh[(64 + tk) * 40 + q4 * 8];
      bf16x8 kil = *(const bf16x8*)&sKl[(64 + tk) * 40 + q4 * 8];
#pragma unroll
      for (int st = 0; st < 2; ++st) {
        f32x4 ar = accr[st][mt], ai = acci[st][mt];
        // sr = qr.kr + qi.ki   (hh + hl + lh)
        ar = mfma16(qh[st][0], krh, ar);
        ar = mfma16(qh[st][0], krl, ar);
        ar = mfma16(ql2[st][0], krh, ar);
        ar = mfma16(qh[st][1], kih, ar);
        ar = mfma16(qh[st][1], kil, ar);
        ar = mfma16(ql2[st][1], kih, ar);
        // si = qi.kr - qr.ki
        ai = mfma16(qh[st][1], krh, ai);
        ai = mfma16(qh[st][1], krl, ai);
        ai = mfma16(ql2[st][1], krh, ai);
        ai = mfma16(nqh[st], kih, ai);
        ai = mfma16(nqh[st], kil, ai);
        ai = mfma16(nql[st], kih, ai);
        accr[st][mt] = ar; acci[st][mt] = ai;
      }
    }
    __syncthreads();
  }

#pragma unroll
  for (int st = 0; st < 2; ++st)
#pragma unroll
    for (int mt = 0; mt < 4; ++mt)
#pragma unroll
      for (int r = 0; r < 4; ++r) {
        int n = n0 + w * 32 + st * 16 + q4 * 4 + r;
        int m = m0 + mt * 16 + ln;
        int idx = (b << 16) + (n << 8) + m;
        atomicAdd(&SR[idx], accr[st][mt][r]);
        atomicAdd(&SI[idx], acci[st][mt][r]);
      }
}

// ---------------- softmax over n (axis=1), per (b,m) column -----------------
__global__ __launch_bounds__(256) void softmax_kernel(
    const float* __restrict__ sr, const float* __restrict__ si,
    float* __restrict__ am)
{
  const int m = blockIdx.x & 255;
  const int b = blockIdx.x >> 8;
  const int n = threadIdx.x;
  const int idx = (b << 16) + (n << 8) + m;
  float vr = sr[idx], vi = si[idx];
  float mag = sqrtf(vr * vr + vi * vi);
  __shared__ float wmax[4];
  __shared__ float wsum[4];
  float mx = mag;
  #pragma unroll
  for (int off = 1; off < 64; off <<= 1)
    mx = fmaxf(mx, __shfl_xor(mx, off, 64));
  if ((threadIdx.x & 63) == 0) wmax[threadIdx.x >> 6] = mx;
  __syncthreads();
  mx = fmaxf(fmaxf(wmax[0], wmax[1]), fmaxf(wmax[2], wmax[3]));
  float e = expf(mag - mx);
  float sm = e;
  #pragma unroll
  for (int off = 1; off < 64; off <<= 1)
    sm += __shfl_xor(sm, off, 64);
  if ((threadIdx.x & 63) == 0) wsum[threadIdx.x >> 6] = sm;
  __syncthreads();
  float tot = wsum[0] + wsum[1] + wsum[2] + wsum[3];
  am[idx] = e / tot;
}

// ---------------- out[d,n] = sum_m a[n,m] * v[d,m] --------------------------
__global__ __launch_bounds__(256) void av_kernel(
    const float* __restrict__ am, const float* __restrict__ v,
    float* __restrict__ out, int freq, int accum)
{
  __shared__ float sV[32][68];
  __shared__ float sA[32][68];
  const int tid = threadIdx.x;
  const int d0 = blockIdx.x << 6;
  const int n0 = blockIdx.y << 6;
  const int bp = blockIdx.z;
  const int b = bp >> 1;
  const float* vp = v + (size_t)bp * PLANE;
  float* op = out + (size_t)bp * PLANE;
  const int td = tid & 15, tn = tid >> 4;

  float acc[16];
  #pragma unroll
  for (int z = 0; z < 16; ++z) acc[z] = 0.f;

  for (int m0 = 0; m0 < 256; m0 += 32) {
    for (int i = tid; i < 2048; i += 256) {
      int dl, mj;
      size_t addr;
      if (!freq) { mj = i & 31; dl = i >> 5;
                   addr = (size_t)(d0 + dl) * 256 + m0 + mj; }
      else       { dl = i & 63; mj = i >> 6;
                   int dg = d0 + dl;
                   addr = (size_t)(dg >> 8) * 65536 + (dg & 255) + (size_t)(m0 + mj) * 256; }
      sV[mj][dl] = vp[addr];
    }
    for (int i = tid; i < 2048; i += 256) {
      int mj = i & 31, nl = i >> 5;
      sA[mj][nl] = am[(b << 16) + ((n0 + nl) << 8) + m0 + mj];
    }
    __syncthreads();
    for (int mm = 0; mm < 32; ++mm) {
      float vv[4], aa[4];
      *(float4*)vv = *(const float4*)&sV[mm][td << 2];
      *(float4*)aa = *(const float4*)&sA[mm][tn << 2];
      #pragma unroll
      for (int ni = 0; ni < 4; ++ni)
        #pragma unroll
        for (int di = 0; di < 4; ++di)
          acc[ni * 4 + di] += aa[ni] * vv[di];
    }
    __syncthreads();
  }

  if (!freq) {
    #pragma unroll
    for (int di = 0; di < 4; ++di) {
      float4 w = make_float4(acc[0 + di], acc[4 + di], acc[8 + di], acc[12 + di]);
      size_t addr = (size_t)(d0 + (td << 2) + di) * 256 + n0 + (tn << 2);
      if (accum) { float4 o = *(float4*)&op[addr];
                   w.x += o.x; w.y += o.y; w.z += o.z; w.w += o.w; }
      *(float4*)&op[addr] = w;
    }
  } else {
    int c = d0 >> 8;
    int t0 = (d0 & 255) + (td << 2);
    #pragma unroll
    for (int ni = 0; ni < 4; ++ni) {
      float4 w = make_float4(acc[ni * 4 + 0], acc[ni * 4 + 1],
                             acc[ni * 4 + 2], acc[ni * 4 + 3]);
      size_t addr = (size_t)c * 65536 + (size_t)(n0 + (tn << 2) + ni) * 256 + t0;
      if (accum) { float4 o = *(float4*)&op[addr];
                   w.x += o.x; w.y += o.y; w.z += o.z; w.w += o.w; }
      *(float4*)&op[addr] = w;
    }
  }
}

extern "C" void kernel_launch(void* const* d_in, const int* in_sizes, int n_in,
                              void* d_out, int out_size, void* d_ws, size_t ws_size,
                              hipStream_t stream) {
  const float* P    = (const float*)d_in[0];
  const float* Q    = (const float*)d_in[1];
  const float* W    = (const float*)d_in[2];
  const float* bias = (const float*)d_in[3];
  const float* g    = (const float*)d_in[4];
  const float* beta = (const float*)d_in[5];
  float* out = (float*)d_out;
  float* ws  = (float*)d_ws;

  float* Y0    = ws;
  float* Y1    = Y0 + TEN_ELEMS;
  float* Y2    = Y1 + TEN_ELEMS;
  float* SR    = Y2 + TEN_ELEMS;
  float* SI    = SR + 131072;
  float* AM    = SI + 131072;
  float* STATS = AM + 131072;
  float* SCALE = STATS + 768;
  float* SHIFT = SCALE + 384;

  for (int phase = 0; phase < 2; ++phase) {
    int j0 = phase * 3;
    int freq = phase;
    hipMemsetAsync(STATS, 0, 768 * sizeof(float), stream);
    cconv_mfma<<<dim3(1024, 2), 256, 0, stream>>>(
        Q, W + (size_t)j0 * 8192, bias + j0 * 128, Y0, STATS);
    cconv_mfma<<<dim3(1024, 2), 256, 0, stream>>>(
        P, W + (size_t)(j0 + 1) * 8192, bias + (j0 + 1) * 128, Y1, STATS + 256);
    cconv_mfma<<<dim3(1024, 2), 256, 0, stream>>>(
        P, W + (size_t)(j0 + 2) * 8192, bias + (j0 + 2) * 128, Y2, STATS + 512);
    bn_finalize<<<2, 256, 0, stream>>>(STATS, g, beta, j0 * 128, SCALE, SHIFT);
    bn_apply<<<49152, 256, 0, stream>>>(Y0, SCALE, SHIFT);   // covers Y0..Y2
    hipMemsetAsync(SR, 0, 2 * 131072 * sizeof(float), stream);
    score_mfma<<<dim3(8, 16, 2), 256, 0, stream>>>(Y0, Y1, SR, SI, freq);
    softmax_kernel<<<512, 256, 0, stream>>>(SR, SI, AM);
    av_kernel<<<dim3(256, 4, 4), 256, 0, stream>>>(AM, Y2, out, freq, phase);
  }
}

// Round 5
// 1117.727 us; speedup vs baseline: 5.8949x; 2.9315x over previous
//
#include <hip/hip_runtime.h>
#include <math.h>

#define SS 65536               // F*T
#define PLANE 4194304          // CC*SS floats per (b,part)
#define TEN_ELEMS 16777216     // 2*2*CC*SS floats per tensor
#define NBUCKET 64

typedef __bf16 bf16x8 __attribute__((ext_vector_type(8)));
typedef __bf16 bf16x4v __attribute__((ext_vector_type(4)));
typedef float  f32x4  __attribute__((ext_vector_type(4)));

__device__ inline f32x4 mfma16(bf16x8 a, bf16x8 b, f32x4 c) {
  return __builtin_amdgcn_mfma_f32_16x16x32_bf16(a, b, c, 0, 0, 0);
}
__device__ inline bf16x8 neg8(bf16x8 v) {
  union { bf16x8 b; unsigned u[4]; } t; t.b = v;
#pragma unroll
  for (int i = 0; i < 4; ++i) t.u[i] ^= 0x80008000u;
  return t.b;
}

// ============ complex 1x1 conv (split-bf16 MFMA) + bias + BN stats ==========
// part: bucketed partial stats, part[bucket*768 + row*2 + s], bucket=blockIdx.x&63
__global__ __launch_bounds__(256) void cconv_mfma(
    const float* __restrict__ x, const float* __restrict__ Wj,
    const float* __restrict__ bias, float* __restrict__ y,
    float* __restrict__ part)
{
  __shared__ __align__(16) __bf16 sBh[64 * 136];   // [s][pc] hi
  __shared__ __align__(16) __bf16 sBl[64 * 136];   // [s][pc] lo
  const int tid = threadIdx.x;
  const int b = blockIdx.y;
  const int s0 = blockIdx.x << 6;
  const int bkt = (blockIdx.x & (NBUCKET - 1)) * 768;
  const int w = tid >> 6, q = (tid >> 4) & 3, ln = tid & 15;

  bf16x8 ah[2][4], al[2][4];
#pragma unroll
  for (int mt = 0; mt < 2; ++mt) {
    int row = w * 32 + mt * 16 + ln;
    int po = row >> 6, co = row & 63;
#pragma unroll
    for (int ks = 0; ks < 4; ++ks) {
      bf16x8 vh, vl;
#pragma unroll
      for (int j = 0; j < 8; ++j) {
        int k = ks * 32 + q * 8 + j;
        int pi = k >> 6, c = k & 63;
        float v = Wj[((po ^ pi) << 12) + co * 64 + c];
        if (po == 0 && pi == 1) v = -v;
        __bf16 h = (__bf16)v;
        vh[j] = h;
        vl[j] = (__bf16)(v - (float)h);
      }
      ah[mt][ks] = vh; al[mt][ks] = vl;
    }
  }

#pragma unroll
  for (int ph = 0; ph < 2; ++ph) {
    int pc = ph * 64 + (tid & 63);
    const float* rowp = x + (size_t)(b * 128 + pc) * SS + s0;
#pragma unroll
    for (int sh2 = 0; sh2 < 2; ++sh2)
#pragma unroll
      for (int sc2 = 0; sc2 < 2; ++sc2) {
        int sl = ((tid >> 6) << 3) + sh2 * 32 + sc2 * 4;
        float4 rd = *(const float4*)&rowp[sl];
        float vv[4] = {rd.x, rd.y, rd.z, rd.w};
#pragma unroll
        for (int e = 0; e < 4; ++e) {
          __bf16 h = (__bf16)vv[e];
          sBh[(sl + e) * 136 + pc] = h;
          sBl[(sl + e) * 136 + pc] = (__bf16)(vv[e] - (float)h);
        }
      }
  }
  __syncthreads();

  f32x4 zero = {0.f, 0.f, 0.f, 0.f};
  f32x4 acc[2][4];
#pragma unroll
  for (int mt = 0; mt < 2; ++mt)
#pragma unroll
    for (int nt = 0; nt < 4; ++nt) acc[mt][nt] = zero;

#pragma unroll
  for (int ks = 0; ks < 4; ++ks) {
    bf16x8 bh[4], bl[4];
#pragma unroll
    for (int nt = 0; nt < 4; ++nt) {
      int off = (nt * 16 + ln) * 136 + ks * 32 + q * 8;
      bh[nt] = *(const bf16x8*)&sBh[off];
      bl[nt] = *(const bf16x8*)&sBl[off];
    }
#pragma unroll
    for (int mt = 0; mt < 2; ++mt)
#pragma unroll
      for (int nt = 0; nt < 4; ++nt) {
        acc[mt][nt] = mfma16(ah[mt][ks], bh[nt], acc[mt][nt]);
        acc[mt][nt] = mfma16(ah[mt][ks], bl[nt], acc[mt][nt]);
        acc[mt][nt] = mfma16(al[mt][ks], bh[nt], acc[mt][nt]);
      }
  }

#pragma unroll
  for (int mt = 0; mt < 2; ++mt) {
    int rowb = w * 32 + mt * 16 + q * 4;
#pragma unroll
    for (int r = 0; r < 4; ++r) {
      float bv = bias[rowb + r];
      float vs[4];
      float sm = 0.f, sq = 0.f;
#pragma unroll
      for (int nt = 0; nt < 4; ++nt) {
        float v = acc[mt][nt][r] + bv;
        vs[nt] = v; sm += v; sq += v * v;
      }
#pragma unroll
      for (int off = 1; off < 16; off <<= 1) {
        sm += __shfl_xor(sm, off, 64);
        sq += __shfl_xor(sq, off, 64);
      }
      if (ln == 0) {
        atomicAdd(&part[bkt + (rowb + r) * 2 + 0], sm);
        atomicAdd(&part[bkt + (rowb + r) * 2 + 1], sq);
      }
#pragma unroll
      for (int nt = 0; nt < 4; ++nt)
        y[(size_t)((b << 7) + rowb + r) * SS + s0 + nt * 16 + ln] = vs[nt];
    }
  }
}

// ---------------- BN finalize (reduce buckets) ------------------------------
__global__ void bn_finalize(const float* __restrict__ buckets,
                            const float* __restrict__ g,
                            const float* __restrict__ beta, int goff,
                            float* __restrict__ scale, float* __restrict__ shift)
{
  int i = blockIdx.x * 256 + threadIdx.x;   // 0..383 = [role3][p][co]
  if (i >= 384) return;
  int role = i >> 7, pc = i & 127;
  float sm = 0.f, sq = 0.f;
  const float* bp = buckets + role * 256 + pc * 2;
#pragma unroll 4
  for (int k = 0; k < NBUCKET; ++k) {
    sm += bp[k * 768 + 0];
    sq += bp[k * 768 + 1];
  }
  const float inv = 1.f / 131072.f;
  float mu = sm * inv;
  float var = sq * inv - mu * mu;
  float istd = rsqrtf(var + 1e-5f);
  float gg = g[goff + role * 128 + pc];
  float bb = beta[goff + role * 128 + pc];
  float sc = gg * istd;
  scale[i] = sc;
  shift[i] = bb - mu * sc;
}

// ---------------- BN apply + leaky relu ------------------------------------
__global__ __launch_bounds__(256) void bn_apply(
    float* __restrict__ y, const float* __restrict__ scale,
    const float* __restrict__ shift)
{
  size_t i = (size_t)blockIdx.x * 256 + threadIdx.x;
  float4 v = ((float4*)y)[i];
  size_t fi = i << 2;
  int idx = (int)(fi >> 24) * 128 + (int)((fi >> 16) & 127);
  float sc = scale[idx], sh = shift[idx];
  float t;
  t = v.x * sc + sh; v.x = t > 0.f ? t : 0.01f * t;
  t = v.y * sc + sh; v.y = t > 0.f ? t : 0.01f * t;
  t = v.z * sc + sh; v.z = t > 0.f ? t : 0.01f * t;
  t = v.w * sc + sh; v.w = t > 0.f ? t : 0.01f * t;
  ((float4*)y)[i] = v;
}

// ============ complex scores (split-bf16 MFMA, split-K, atomics) ============
__global__ __launch_bounds__(256) void score_mfma(
    const float* __restrict__ qg, const float* __restrict__ kg,
    float* __restrict__ SR, float* __restrict__ SI, int freq)
{
  __shared__ __align__(16) __bf16 sQh[2 * 128 * 40], sQl[2 * 128 * 40];
  __shared__ __align__(16) __bf16 sKh[2 * 64 * 40],  sKl[2 * 64 * 40];
  const int tid = threadIdx.x;
  const int n0 = (blockIdx.x >> 2) * 128, m0 = (blockIdx.x & 3) * 64;
  const int d0 = blockIdx.y * 1024;
  const int b = blockIdx.z;
  const int w = tid >> 6, q4 = (tid >> 4) & 3, ln = tid & 15;
  const float* qp = qg + (size_t)b * 2 * PLANE;
  const float* kp = kg + (size_t)b * 2 * PLANE;

  f32x4 zero = {0.f, 0.f, 0.f, 0.f};
  f32x4 accr[2][4], acci[2][4];
#pragma unroll
  for (int st = 0; st < 2; ++st)
#pragma unroll
    for (int mt = 0; mt < 4; ++mt) { accr[st][mt] = zero; acci[st][mt] = zero; }

  for (int ch = 0; ch < 32; ++ch) {
    const int dd = d0 + ch * 32;
    if (!freq) {
#pragma unroll
      for (int r = 0; r < 8; ++r) {
        int u = tid + 256 * r;
        int tok4 = u & 31, dl = (u >> 5) & 31, p = u >> 10;
        float4 v4 = *(const float4*)&qp[(size_t)p * PLANE +
                                        (size_t)(dd + dl) * 256 + n0 + tok4 * 4];
        float vv[4] = {v4.x, v4.y, v4.z, v4.w};
#pragma unroll
        for (int e = 0; e < 4; ++e) {
          __bf16 h = (__bf16)vv[e];
          sQh[(p * 128 + tok4 * 4 + e) * 40 + dl] = h;
          sQl[(p * 128 + tok4 * 4 + e) * 40 + dl] = (__bf16)(vv[e] - (float)h);
        }
      }
#pragma unroll
      for (int r = 0; r < 4; ++r) {
        int u = tid + 256 * r;
        int tok4 = u & 15, dl = (u >> 4) & 31, p = u >> 9;
        float4 v4 = *(const float4*)&kp[(size_t)p * PLANE +
                                        (size_t)(dd + dl) * 256 + m0 + tok4 * 4];
        float vv[4] = {v4.x, v4.y, v4.z, v4.w};
#pragma unroll
        for (int e = 0; e < 4; ++e) {
          __bf16 h = (__bf16)vv[e];
          sKh[(p * 64 + tok4 * 4 + e) * 40 + dl] = h;
          sKl[(p * 64 + tok4 * 4 + e) * 40 + dl] = (__bf16)(vv[e] - (float)h);
        }
      }
    } else {
      const int c = dd >> 8, t0c = dd & 255;
#pragma unroll
      for (int r = 0; r < 8; ++r) {
        int u = tid + 256 * r;
        int dc = u & 7, tok = (u >> 3) & 127, p = u >> 10;
        float4 v4 = *(const float4*)&qp[(size_t)p * PLANE + (size_t)c * 65536 +
                                        t0c + dc * 4 + (size_t)(n0 + tok) * 256];
        float vv[4] = {v4.x, v4.y, v4.z, v4.w};
        bf16x4v hv, lv;
#pragma unroll
        for (int e = 0; e < 4; ++e) {
          __bf16 h = (__bf16)vv[e];
          hv[e] = h; lv[e] = (__bf16)(vv[e] - (float)h);
        }
        *(bf16x4v*)&sQh[(p * 128 + tok) * 40 + dc * 4] = hv;
        *(bf16x4v*)&sQl[(p * 128 + tok) * 40 + dc * 4] = lv;
      }
#pragma unroll
      for (int r = 0; r < 4; ++r) {
        int u = tid + 256 * r;
        int dc = u & 7, tok = (u >> 3) & 63, p = u >> 9;
        float4 v4 = *(const float4*)&kp[(size_t)p * PLANE + (size_t)c * 65536 +
                                        t0c + dc * 4 + (size_t)(m0 + tok) * 256];
        float vv[4] = {v4.x, v4.y, v4.z, v4.w};
        bf16x4v hv, lv;
#pragma unroll
        for (int e = 0; e < 4; ++e) {
          __bf16 h = (__bf16)vv[e];
          hv[e] = h; lv[e] = (__bf16)(vv[e] - (float)h);
        }
        *(bf16x4v*)&sKh[(p * 64 + tok) * 40 + dc * 4] = hv;
        *(bf16x4v*)&sKl[(p * 64 + tok) * 40 + dc * 4] = lv;
      }
    }
    __syncthreads();

    bf16x8 qh[2][2], ql2[2][2], nqh[2], nql[2];
#pragma unroll
    for (int st = 0; st < 2; ++st) {
      int tokn = w * 32 + st * 16 + ln;
#pragma unroll
      for (int p = 0; p < 2; ++p) {
        qh[st][p]  = *(const bf16x8*)&sQh[(p * 128 + tokn) * 40 + q4 * 8];
        ql2[st][p] = *(const bf16x8*)&sQl[(p * 128 + tokn) * 40 + q4 * 8];
      }
      nqh[st] = neg8(qh[st][0]);
      nql[st] = neg8(ql2[st][0]);
    }
#pragma unroll
    for (int mt = 0; mt < 4; ++mt) {
      int tk = mt * 16 + ln;
      bf16x8 krh = *(const bf16x8*)&sKh[tk * 40 + q4 * 8];
      bf16x8 krl = *(const bf16x8*)&sKl[tk * 40 + q4 * 8];
      bf16x8 kih = *(const bf16x8*)&sKh[(64 + tk) * 40 + q4 * 8];
      bf16x8 kil = *(const bf16x8*)&sKl[(64 + tk) * 40 + q4 * 8];
#pragma unroll
      for (int st = 0; st < 2; ++st) {
        f32x4 ar = accr[st][mt], ai = acci[st][mt];
        ar = mfma16(qh[st][0], krh, ar);
        ar = mfma16(qh[st][0], krl, ar);
        ar = mfma16(ql2[st][0], krh, ar);
        ar = mfma16(qh[st][1], kih, ar);
        ar = mfma16(qh[st][1], kil, ar);
        ar = mfma16(ql2[st][1], kih, ar);
        ai = mfma16(qh[st][1], krh, ai);
        ai = mfma16(qh[st][1], krl, ai);
        ai = mfma16(ql2[st][1], krh, ai);
        ai = mfma16(nqh[st], kih, ai);
        ai = mfma16(nqh[st], kil, ai);
        ai = mfma16(nql[st], kih, ai);
        accr[st][mt] = ar; acci[st][mt] = ai;
      }
    }
    __syncthreads();
  }

#pragma unroll
  for (int st = 0; st < 2; ++st)
#pragma unroll
    for (int mt = 0; mt < 4; ++mt)
#pragma unroll
      for (int r = 0; r < 4; ++r) {
        int n = n0 + w * 32 + st * 16 + q4 * 4 + r;
        int m = m0 + mt * 16 + ln;
        int idx = (b << 16) + (n << 8) + m;
        atomicAdd(&SR[idx], accr[st][mt][r]);
        atomicAdd(&SI[idx], acci[st][mt][r]);
      }
}

// ---------------- softmax over n (axis=1), per (b,m) column -----------------
__global__ __launch_bounds__(256) void softmax_kernel(
    const float* __restrict__ sr, const float* __restrict__ si,
    float* __restrict__ am)
{
  const int m = blockIdx.x & 255;
  const int b = blockIdx.x >> 8;
  const int n = threadIdx.x;
  const int idx = (b << 16) + (n << 8) + m;
  float vr = sr[idx], vi = si[idx];
  float mag = sqrtf(vr * vr + vi * vi);
  __shared__ float wmax[4];
  __shared__ float wsum[4];
  float mx = mag;
  #pragma unroll
  for (int off = 1; off < 64; off <<= 1)
    mx = fmaxf(mx, __shfl_xor(mx, off, 64));
  if ((threadIdx.x & 63) == 0) wmax[threadIdx.x >> 6] = mx;
  __syncthreads();
  mx = fmaxf(fmaxf(wmax[0], wmax[1]), fmaxf(wmax[2], wmax[3]));
  float e = expf(mag - mx);
  float sm = e;
  #pragma unroll
  for (int off = 1; off < 64; off <<= 1)
    sm += __shfl_xor(sm, off, 64);
  if ((threadIdx.x & 63) == 0) wsum[threadIdx.x >> 6] = sm;
  __syncthreads();
  float tot = wsum[0] + wsum[1] + wsum[2] + wsum[3];
  am[idx] = e / tot;
}

// ---------------- out[d,n] = sum_m a[n,m] * v[d,m] --------------------------
__global__ __launch_bounds__(256) void av_kernel(
    const float* __restrict__ am, const float* __restrict__ v,
    float* __restrict__ out, int freq, int accum)
{
  __shared__ float sV[32][68];
  __shared__ float sA[32][68];
  const int tid = threadIdx.x;
  const int d0 = blockIdx.x << 6;
  const int n0 = blockIdx.y << 6;
  const int bp = blockIdx.z;
  const int b = bp >> 1;
  const float* vp = v + (size_t)bp * PLANE;
  float* op = out + (size_t)bp * PLANE;
  const int td = tid & 15, tn = tid >> 4;

  float acc[16];
  #pragma unroll
  for (int z = 0; z < 16; ++z) acc[z] = 0.f;

  for (int m0 = 0; m0 < 256; m0 += 32) {
    for (int i = tid; i < 2048; i += 256) {
      int dl, mj;
      size_t addr;
      if (!freq) { mj = i & 31; dl = i >> 5;
                   addr = (size_t)(d0 + dl) * 256 + m0 + mj; }
      else       { dl = i & 63; mj = i >> 6;
                   int dg = d0 + dl;
                   addr = (size_t)(dg >> 8) * 65536 + (dg & 255) + (size_t)(m0 + mj) * 256; }
      sV[mj][dl] = vp[addr];
    }
    for (int i = tid; i < 2048; i += 256) {
      int mj = i & 31, nl = i >> 5;
      sA[mj][nl] = am[(b << 16) + ((n0 + nl) << 8) + m0 + mj];
    }
    __syncthreads();
    for (int mm = 0; mm < 32; ++mm) {
      float vv[4], aa[4];
      *(float4*)vv = *(const float4*)&sV[mm][td << 2];
      *(float4*)aa = *(const float4*)&sA[mm][tn << 2];
      #pragma unroll
      for (int ni = 0; ni < 4; ++ni)
        #pragma unroll
        for (int di = 0; di < 4; ++di)
          acc[ni * 4 + di] += aa[ni] * vv[di];
    }
    __syncthreads();
  }

  if (!freq) {
    #pragma unroll
    for (int di = 0; di < 4; ++di) {
      float4 w = make_float4(acc[0 + di], acc[4 + di], acc[8 + di], acc[12 + di]);
      size_t addr = (size_t)(d0 + (td << 2) + di) * 256 + n0 + (tn << 2);
      if (accum) { float4 o = *(float4*)&op[addr];
                   w.x += o.x; w.y += o.y; w.z += o.z; w.w += o.w; }
      *(float4*)&op[addr] = w;
    }
  } else {
    int c = d0 >> 8;
    int t0 = (d0 & 255) + (td << 2);
    #pragma unroll
    for (int ni = 0; ni < 4; ++ni) {
      float4 w = make_float4(acc[ni * 4 + 0], acc[ni * 4 + 1],
                             acc[ni * 4 + 2], acc[ni * 4 + 3]);
      size_t addr = (size_t)c * 65536 + (size_t)(n0 + (tn << 2) + ni) * 256 + t0;
      if (accum) { float4 o = *(float4*)&op[addr];
                   w.x += o.x; w.y += o.y; w.z += o.z; w.w += o.w; }
      *(float4*)&op[addr] = w;
    }
  }
}

extern "C" void kernel_launch(void* const* d_in, const int* in_sizes, int n_in,
                              void* d_out, int out_size, void* d_ws, size_t ws_size,
                              hipStream_t stream) {
  const float* P    = (const float*)d_in[0];
  const float* Q    = (const float*)d_in[1];
  const float* W    = (const float*)d_in[2];
  const float* bias = (const float*)d_in[3];
  const float* g    = (const float*)d_in[4];
  const float* beta = (const float*)d_in[5];
  float* out = (float*)d_out;
  float* ws  = (float*)d_ws;

  float* Y0    = ws;
  float* Y1    = Y0 + TEN_ELEMS;
  float* Y2    = Y1 + TEN_ELEMS;
  float* SR    = Y2 + TEN_ELEMS;
  float* SI    = SR + 131072;
  float* AM    = SI + 131072;
  float* BUCK  = AM + 131072;             // 64 * 768 = 49152 floats
  float* SCALE = BUCK + NBUCKET * 768;    // 384
  float* SHIFT = SCALE + 384;             // 384

  for (int phase = 0; phase < 2; ++phase) {
    int j0 = phase * 3;
    int freq = phase;
    hipMemsetAsync(BUCK, 0, NBUCKET * 768 * sizeof(float), stream);
    cconv_mfma<<<dim3(1024, 2), 256, 0, stream>>>(
        Q, W + (size_t)j0 * 8192, bias + j0 * 128, Y0, BUCK);
    cconv_mfma<<<dim3(1024, 2), 256, 0, stream>>>(
        P, W + (size_t)(j0 + 1) * 8192, bias + (j0 + 1) * 128, Y1, BUCK + 256);
    cconv_mfma<<<dim3(1024, 2), 256, 0, stream>>>(
        P, W + (size_t)(j0 + 2) * 8192, bias + (j0 + 2) * 128, Y2, BUCK + 512);
    bn_finalize<<<2, 256, 0, stream>>>(BUCK, g, beta, j0 * 128, SCALE, SHIFT);
    bn_apply<<<49152, 256, 0, stream>>>(Y0, SCALE, SHIFT);   // covers Y0..Y2
    hipMemsetAsync(SR, 0, 2 * 131072 * sizeof(float), stream);
    score_mfma<<<dim3(8, 16, 2), 256, 0, stream>>>(Y0, Y1, SR, SI, freq);
    softmax_kernel<<<512, 256, 0, stream>>>(SR, SI, AM);
    av_kernel<<<dim3(256, 4, 4), 256, 0, stream>>>(AM, Y2, out, freq, phase);
  }
}